// Round 2
// baseline (423.016 us; speedup 1.0000x reference)
//
#include <hip/hip_runtime.h>
#include <math.h>

// Problem constants (fixed by reference):
#define N_  2
#define S_  1024       // seq len == L
#define H_  12
#define D_  64         // head dim == M
#define HIDDEN_ 768    // H_*D_
#define EPS_ 1e-6f

#define CHUNK 64          // s-rows per pv block
#define NS    (S_/CHUNK)  // 16 s-chunks

// elu(x)+1  (alpha=1): x>0 ? x+1 : exp(x)
__device__ __forceinline__ float elup1(float x) {
    return x > 0.0f ? x + 1.0f : __expf(x);
}

// ---------------------------------------------------------------------------
// Kernel 1: per-chunk partials (deterministic, no atomics):
//   pv_part[n,h,sc,m,d] = sum_{s in chunk sc} p[n,s,h,d] * v[n,s,h,m]
//   psum_part[n,h,sc,d] = sum_{s in chunk sc} p[n,s,h,d]
// grid = N_*H_*NS blocks of 256 threads.
// ---------------------------------------------------------------------------
__global__ __launch_bounds__(256) void pv_kernel(
        const float* __restrict__ v,      // [N,S,H,D]
        const float* __restrict__ mask,   // [N,S]
        const float* __restrict__ w,      // [S,HIDDEN]
        float* __restrict__ pv_part,      // [N,H,NS,64,64]
        float* __restrict__ psum_part) {  // [N,H,NS,64]
    __shared__ float p_lds[CHUNK * 64];
    __shared__ float v_lds[CHUNK * 64];

    const int b  = blockIdx.x;
    const int sc = b % NS;
    const int h  = (b / NS) % H_;
    const int n  = b / (NS * H_);
    const int s0 = sc * CHUNK;
    const int t  = threadIdx.x;

    // Stage p-chunk (elu+mask applied) and v-chunk into LDS via float4 loads.
    for (int j = t; j < CHUNK * 16; j += 256) {
        const int row = j >> 4;
        const int c4  = (j & 15) * 4;
        const int s   = s0 + row;
        const float m = mask[n * S_ + s];
        const float4 wv = *(const float4*)(w + (size_t)s * HIDDEN_ + h * 64 + c4);
        float4 p;
        p.x = elup1(wv.x) * m;
        p.y = elup1(wv.y) * m;
        p.z = elup1(wv.z) * m;
        p.w = elup1(wv.w) * m;
        *(float4*)(p_lds + row * 64 + c4) = p;
        const float4 vv = *(const float4*)(v + (((size_t)n * S_ + s) * H_ + h) * 64 + c4);
        *(float4*)(v_lds + row * 64 + c4) = vv;
    }
    __syncthreads();

    // Outer-product accumulate: thread (d = t&63, mq = t>>6) owns m = mq*16..+15.
    const int d  = t & 63;
    const int mq = t >> 6;
    float acc[16];
    #pragma unroll
    for (int i = 0; i < 16; ++i) acc[i] = 0.0f;
    float ps = 0.0f;

    for (int s = 0; s < CHUNK; ++s) {
        const float pd = p_lds[s * 64 + d];          // stride-1: conflict-free
        ps += pd;
        const float* vr = v_lds + s * 64 + mq * 16;  // wave-uniform: broadcast
        #pragma unroll
        for (int i = 0; i < 16; ++i)
            acc[i] = fmaf(pd, vr[i], acc[i]);
    }

    float* pvp = pv_part + (((size_t)(n * H_ + h)) * NS + sc) * (64 * 64);
    #pragma unroll
    for (int i = 0; i < 16; ++i)
        pvp[(mq * 16 + i) * 64 + d] = acc[i];        // coalesced stores
    if (mq == 0)
        psum_part[(((size_t)(n * H_ + h)) * NS + sc) * 64 + d] = ps;
}

// ---------------------------------------------------------------------------
// Kernel 2: reduce the NS chunk-partials.
//   pv[n,h,m,d]  = sum_sc pv_part[n,h,sc,m,d]
//   psum[n,h,d]  = sum_sc psum_part[n,h,sc,d]
// grid = N_*H_ blocks of 256 threads; thread t owns elements t+k*256, k<16.
// ---------------------------------------------------------------------------
__global__ __launch_bounds__(256) void reduce_kernel(
        const float* __restrict__ pv_part,    // [N,H,NS,64,64]
        const float* __restrict__ psum_part,  // [N,H,NS,64]
        float* __restrict__ pv_ws,            // [N,H,64,64]
        float* __restrict__ psum_ws) {        // [N,H,64]
    const int nh = blockIdx.x;
    const int t  = threadIdx.x;
    const float* src = pv_part + (size_t)nh * NS * 4096;
    float* dst = pv_ws + (size_t)nh * 4096;

    #pragma unroll
    for (int k = 0; k < 16; ++k) {
        const int e = t + k * 256;
        float s = 0.0f;
        #pragma unroll
        for (int sc = 0; sc < NS; ++sc)
            s += src[(size_t)sc * 4096 + e];
        dst[e] = s;
    }
    if (t < 64) {
        const float* ps = psum_part + (size_t)nh * NS * 64;
        float s = 0.0f;
        #pragma unroll
        for (int sc = 0; sc < NS; ++sc)
            s += ps[sc * 64 + t];
        psum_ws[nh * 64 + t] = s;
    }
}

// ---------------------------------------------------------------------------
// Kernel 3: one block per (n,l,h).
//   ppv[n,l,h,m,d] = p[n,l,h,d] * pv[n,h,m,d] * head_mask[h]   (16KB tile)
//   z_pp[n,l,h]    = sum_d p[n,l,h,d] * psum[n,h,d] + EPS
// blockIdx.x == ((n*L + l)*H + h).
// ---------------------------------------------------------------------------
__global__ __launch_bounds__(256) void ppv_kernel(
        const float* __restrict__ w,         // [S,HIDDEN]
        const float* __restrict__ mask,      // [N,S]
        const float* __restrict__ head_mask, // [H]
        const float* __restrict__ pv_ws,     // [N,H,64,64]
        const float* __restrict__ psum_ws,   // [N,H,64]
        float* __restrict__ ppv_out,         // [N,L,H,64,64]
        float* __restrict__ z_out) {         // [N,L,H]
    __shared__ float p_l[64];

    const int b = blockIdx.x;
    const int h = b % H_;
    const int l = (b / H_) % S_;
    const int n = b / (H_ * S_);
    const int t = threadIdx.x;

    if (t < 64) {
        const float x = w[(size_t)l * HIDDEN_ + h * 64 + t];
        const float m = mask[n * S_ + l];
        const float p = elup1(x) * m;
        p_l[t] = p;
        // z_pp wave reduction (lanes 0..63 of wave 0)
        float pz = p * psum_ws[(n * H_ + h) * 64 + t];
        #pragma unroll
        for (int off = 32; off > 0; off >>= 1)
            pz += __shfl_down(pz, off, 64);
        if (t == 0) z_out[b] = pz + EPS_;
    }
    __syncthreads();

    const float hm = head_mask[h];
    const float4* pv4 = (const float4*)(pv_ws + ((size_t)n * H_ + h) * (64 * 64));
    float4* out4 = (float4*)(ppv_out + (size_t)b * (64 * 64));

    #pragma unroll
    for (int jj = 0; jj < 4; ++jj) {
        const int j = t + jj * 256;           // float4 index within 1024
        const float4 vv = pv4[j];             // L2-resident after first touch
        const float4 pw = *(const float4*)(p_l + ((j * 4) & 63));
        float4 r;
        r.x = pw.x * vv.x * hm;
        r.y = pw.y * vv.y * hm;
        r.z = pw.z * vv.z * hm;
        r.w = pw.w * vv.w * hm;
        out4[j] = r;                          // coalesced 16B/lane stores
    }
}

extern "C" void kernel_launch(void* const* d_in, const int* in_sizes, int n_in,
                              void* d_out, int out_size, void* d_ws, size_t ws_size,
                              hipStream_t stream) {
    // setup_inputs order: q, v, attention_mask, head_mask, pos_weight
    const float* v     = (const float*)d_in[1];
    const float* mask  = (const float*)d_in[2];
    const float* hmask = (const float*)d_in[3];
    const float* w     = (const float*)d_in[4];
    float* out = (float*)d_out;

    // ws layout (floats):
    //   pv_part   : N*H*NS*64*64   = 1,572,864
    //   psum_part : N*H*NS*64      = 24,576
    //   pv_ws     : N*H*64*64      = 98,304
    //   psum_ws   : N*H*64         = 1,536
    float* pv_part   = (float*)d_ws;
    float* psum_part = pv_part + (size_t)N_ * H_ * NS * 64 * 64;
    float* pv_ws     = psum_part + (size_t)N_ * H_ * NS * 64;
    float* psum_ws   = pv_ws + (size_t)N_ * H_ * 64 * 64;

    pv_kernel<<<dim3(N_ * H_ * NS), dim3(256), 0, stream>>>(
        v, mask, w, pv_part, psum_part);

    reduce_kernel<<<dim3(N_ * H_), dim3(256), 0, stream>>>(
        pv_part, psum_part, pv_ws, psum_ws);

    float* z_out = out + (size_t)N_ * S_ * H_ * 64 * 64;
    ppv_kernel<<<dim3(N_ * S_ * H_), dim3(256), 0, stream>>>(
        w, mask, hmask, pv_ws, psum_ws, out, z_out);
}